// Round 1
// baseline (284.453 us; speedup 1.0000x reference)
//
#include <hip/hip_runtime.h>

#define N_ 16
#define C_ 128
#define HW_ 16384
#define K_ 1638   // int(0.1 * 16384)

// order-preserving float -> uint key (larger key <=> larger float)
__device__ __forceinline__ unsigned f2k(float f) {
    unsigned u = __float_as_uint(f);
    return (u & 0x80000000u) ? ~u : (u | 0x80000000u);
}

// Kernel 1: col_stats[n][p] = mean over c of x[n][c][p], fp64 accumulation.
// One thread per 4 columns (float4 loads along p, coalesced).
__global__ void col_mean_kernel(const float* __restrict__ x, float* __restrict__ cs) {
    int id = blockIdx.x * blockDim.x + threadIdx.x;   // [0, N_*HW_/4)
    int n  = id >> 12;                                // HW_/4 = 4096
    int p4 = id & 4095;
    const float4* xp = (const float4*)x + (size_t)n * C_ * 4096 + p4;
    double s0 = 0.0, s1 = 0.0, s2 = 0.0, s3 = 0.0;
    #pragma unroll 8
    for (int cc = 0; cc < C_; ++cc) {
        float4 v = xp[(size_t)cc * 4096];
        s0 += (double)v.x; s1 += (double)v.y; s2 += (double)v.z; s3 += (double)v.w;
    }
    float4 r;
    const double inv = 1.0 / (double)C_;
    r.x = (float)(s0 * inv); r.y = (float)(s1 * inv);
    r.z = (float)(s2 * inv); r.w = (float)(s3 * inv);
    ((float4*)cs)[id] = r;
}

__device__ __forceinline__ unsigned block_reduce_sum_1024(unsigned v, unsigned* sh) {
    // wave (64-lane) reduce
    for (int o = 32; o > 0; o >>= 1) v += __shfl_down(v, o, 64);
    int lane = threadIdx.x & 63;
    int wid  = threadIdx.x >> 6;   // 16 waves
    __syncthreads();               // protect sh reuse across calls
    if (lane == 0) sh[wid] = v;
    __syncthreads();
    if (threadIdx.x == 0) {
        unsigned tot = 0;
        #pragma unroll
        for (int i = 0; i < 16; ++i) tot += sh[i];
        sh[16] = tot;
    }
    __syncthreads();
    return sh[16];
}

// Kernel 2: per-sample exact k-th-largest via 32-step radix select over
// order-preserving keys held in LDS. meta[n] = {thresh_key, t, e}
//  t = number of elements equal to thresh that belong in top-k
//  e = total number of elements equal to thresh
__global__ void __launch_bounds__(1024) select_kernel(const float* __restrict__ cs,
                                                      unsigned* __restrict__ meta) {
    __shared__ unsigned keys[HW_];
    __shared__ unsigned sh[32];
    int n = blockIdx.x;
    for (int i = threadIdx.x; i < HW_; i += 1024) keys[i] = f2k(cs[n * HW_ + i]);
    __syncthreads();

    unsigned prefix = 0, need = K_;
    for (int b = 31; b >= 0; --b) {
        unsigned cand_hi = (prefix >> b) | 1u;
        unsigned cnt = 0;
        for (int i = threadIdx.x; i < HW_; i += 1024)
            cnt += ((keys[i] >> b) == cand_hi) ? 1u : 0u;
        unsigned tot = block_reduce_sum_1024(cnt, sh);
        if (tot >= need) prefix |= (1u << b);
        else             need -= tot;
    }
    // total equal count (for the fast tie path)
    unsigned ec = 0;
    for (int i = threadIdx.x; i < HW_; i += 1024)
        ec += (keys[i] == prefix) ? 1u : 0u;
    unsigned e = block_reduce_sum_1024(ec, sh);

    if (threadIdx.x == 0) {
        meta[n * 4 + 0] = prefix;
        meta[n * 4 + 1] = need;   // t
        meta[n * 4 + 2] = e;
    }
}

// Kernel 3: per-column multiplier. masked -> 1.0 (x stays x), else (1-tau).
// Exact-tie path (e != t): lower index wins, matching lax.top_k.
__global__ void scale_kernel(const float* __restrict__ cs,
                             const unsigned* __restrict__ meta,
                             const float* __restrict__ tau_p,
                             float* __restrict__ scale) {
    int id = blockIdx.x * blockDim.x + threadIdx.x;   // [0, N_*HW_)
    int n = id >> 14;
    int p = id & (HW_ - 1);
    unsigned thresh = meta[n * 4 + 0];
    unsigned t      = meta[n * 4 + 1];
    unsigned e      = meta[n * 4 + 2];
    unsigned kk = f2k(cs[id]);
    int m;
    if (kk > thresh)      m = 1;
    else if (kk < thresh) m = 0;
    else if (e == t)      m = 1;           // all tied elements selected (common case: e==t==1..)
    else {
        // rare: real duplicates at the threshold — index-ordered selection
        unsigned r = 0;
        const float* base = cs + n * HW_;
        for (int q = 0; q < p; ++q) r += (f2k(base[q]) == thresh) ? 1u : 0u;
        m = (r < t) ? 1 : 0;
    }
    float tau = *tau_p;
    scale[id] = m ? 1.0f : (1.0f - tau);
}

// Kernel 4: out[n][c][p] = x[n][c][p] * scale[n][p], float4 vectorized.
__global__ void apply_kernel(const float* __restrict__ x,
                             const float* __restrict__ scale,
                             float* __restrict__ out) {
    int id = blockIdx.x * blockDim.x + threadIdx.x;   // float4 index, [0, N_*C_*HW_/4)
    int n  = id >> 19;                                // C_*HW_/4 = 524288 = 2^19
    int p4 = id & 4095;                               // HW_/4 = 4096
    float4 v = ((const float4*)x)[id];
    float4 s = ((const float4*)scale)[(size_t)n * 4096 + p4];
    v.x *= s.x; v.y *= s.y; v.z *= s.z; v.w *= s.w;
    ((float4*)out)[id] = v;
}

extern "C" void kernel_launch(void* const* d_in, const int* in_sizes, int n_in,
                              void* d_out, int out_size, void* d_ws, size_t ws_size,
                              hipStream_t stream) {
    const float* x     = (const float*)d_in[0];
    const float* tau_p = (const float*)d_in[1];
    float* out = (float*)d_out;

    // workspace layout: cs (1 MiB) | meta (16*4 uints, padded to 1 KiB) | scale (1 MiB)
    char* ws = (char*)d_ws;
    float*    cs    = (float*)ws;
    unsigned* meta  = (unsigned*)(ws + (size_t)N_ * HW_ * sizeof(float));
    float*    scale = (float*)(ws + (size_t)N_ * HW_ * sizeof(float) + 1024);

    // 1) column means: N_*HW_/4 threads
    col_mean_kernel<<<(N_ * HW_ / 4) / 256, 256, 0, stream>>>(x, cs);
    // 2) per-sample radix select
    select_kernel<<<N_, 1024, 0, stream>>>(cs, meta);
    // 3) per-column scale
    scale_kernel<<<(N_ * HW_) / 256, 256, 0, stream>>>(cs, meta, tau_p, scale);
    // 4) apply
    apply_kernel<<<(N_ * C_ * HW_ / 4) / 256, 256, 0, stream>>>(x, scale, out);
}

// Round 2
// 282.940 us; speedup vs baseline: 1.0053x; 1.0053x over previous
//
#include <hip/hip_runtime.h>

#define N_ 16
#define C_ 128
#define HW_ 16384
#define K_ 1638   // int(0.1 * 16384)

// order-preserving float -> uint key (larger key <=> larger float)
__device__ __forceinline__ unsigned f2k(float f) {
    unsigned u = __float_as_uint(f);
    return (u & 0x80000000u) ? ~u : (u | 0x80000000u);
}

// Kernel 1: keys[n][p] = f2k(mean over c of x[n][c][p]), fp64 accumulation.
// One thread per 4 columns (float4 loads along p, coalesced).
__global__ __launch_bounds__(256) void col_mean_kernel(const float* __restrict__ x,
                                                       unsigned* __restrict__ keys_g) {
    int id = blockIdx.x * blockDim.x + threadIdx.x;   // [0, N_*HW_/4)
    int n  = id >> 12;                                // HW_/4 = 4096
    int p4 = id & 4095;
    const float4* xp = (const float4*)x + (size_t)n * C_ * 4096 + p4;
    double s0 = 0.0, s1 = 0.0, s2 = 0.0, s3 = 0.0;
    #pragma unroll 16
    for (int cc = 0; cc < C_; ++cc) {
        float4 v = xp[(size_t)cc * 4096];
        s0 += (double)v.x; s1 += (double)v.y; s2 += (double)v.z; s3 += (double)v.w;
    }
    const double inv = 1.0 / (double)C_;
    uint4 r;
    r.x = f2k((float)(s0 * inv)); r.y = f2k((float)(s1 * inv));
    r.z = f2k((float)(s2 * inv)); r.w = f2k((float)(s3 * inv));
    ((uint4*)keys_g)[id] = r;
}

// Kernel 2: per-sample exact top-k threshold via 4-pass 256-bin radix select,
// then write per-column byte mask (1 = selected). One block (256 thr) per sample.
// Tie-break matches lax.top_k: among keys equal to threshold, lowest index wins.
__global__ __launch_bounds__(256) void select_mask_kernel(const unsigned* __restrict__ keys_g,
                                                          unsigned char* __restrict__ mask) {
    __shared__ unsigned keys[HW_];      // 64 KiB
    __shared__ unsigned hist[256];
    __shared__ unsigned scanb[256];
    __shared__ unsigned Sarr[257];
    __shared__ unsigned sel[2];
    const int t = threadIdx.x;
    const int n = blockIdx.x;

    // load keys (uint4 = 16B per load)
    const uint4* kg = (const uint4*)(keys_g + (size_t)n * HW_);
    for (int i = t; i < HW_ / 4; i += 256) ((uint4*)keys)[i] = kg[i];
    __syncthreads();

    unsigned prefix = 0, need = K_;
    for (int pass = 0; pass < 4; ++pass) {
        const int shift = 24 - 8 * pass;
        const unsigned himask = (pass == 0) ? 0u : (0xFFFFFFFFu << (shift + 8));

        hist[t] = 0;
        __syncthreads();
        for (int i = t; i < HW_; i += 256) {
            unsigned k = keys[i];
            if (((k ^ prefix) & himask) == 0)
                atomicAdd(&hist[(k >> shift) & 255], 1u);
        }
        __syncthreads();

        // suffix sums over 256 bins: S[b] = count of candidates with bin >= b
        unsigned v = hist[t];
        #pragma unroll
        for (int off = 1; off < 256; off <<= 1) {
            scanb[t] = v;
            __syncthreads();
            if (t + off < 256) v += scanb[t + off];
            __syncthreads();
        }
        Sarr[t] = v;
        if (t == 0) Sarr[256] = 0;
        __syncthreads();
        // unique b with S[b] >= need > S[b+1]
        if (Sarr[t] >= need && Sarr[t + 1] < need) {
            sel[0] = (unsigned)t;
            sel[1] = need - Sarr[t + 1];
        }
        __syncthreads();
        prefix |= sel[0] << shift;
        need = sel[1];
        __syncthreads();
    }
    const unsigned thresh = prefix;   // exact 32-bit k-th largest key
    const unsigned t_keep = need;     // # of ==thresh elements to keep (lowest indices)

    // ordered rank among equals: thread t owns contiguous chunk [t*64, t*64+64)
    unsigned cnt = 0;
    const int base_i = t * 64;
    for (int j = 0; j < 64; ++j) cnt += (keys[base_i + j] == thresh) ? 1u : 0u;
    unsigned pv = cnt;
    #pragma unroll
    for (int off = 1; off < 256; off <<= 1) {
        scanb[t] = pv;
        __syncthreads();
        if (t >= off) pv += scanb[t - off];
        __syncthreads();
    }
    const unsigned excl = pv - cnt;   // equals before this chunk (index order)

    unsigned packed[16];
    #pragma unroll
    for (int w = 0; w < 16; ++w) packed[w] = 0;
    unsigned local = 0;
    for (int j = 0; j < 64; ++j) {
        unsigned k = keys[base_i + j];
        unsigned m;
        if (k > thresh) m = 1u;
        else if (k == thresh) { m = ((excl + local) < t_keep) ? 1u : 0u; ++local; }
        else m = 0u;
        packed[j >> 2] |= m << ((j & 3) * 8);
    }
    uint4* mp = (uint4*)(mask + (size_t)n * HW_ + base_i);
    mp[0] = make_uint4(packed[0],  packed[1],  packed[2],  packed[3]);
    mp[1] = make_uint4(packed[4],  packed[5],  packed[6],  packed[7]);
    mp[2] = make_uint4(packed[8],  packed[9],  packed[10], packed[11]);
    mp[3] = make_uint4(packed[12], packed[13], packed[14], packed[15]);
}

// Kernel 3: out[n][c][p] = mask ? x : x*(1-tau), float4 vectorized.
__global__ __launch_bounds__(256) void apply_kernel(const float* __restrict__ x,
                                                    const unsigned char* __restrict__ mask,
                                                    const float* __restrict__ tau_p,
                                                    float* __restrict__ out) {
    int id = blockIdx.x * blockDim.x + threadIdx.x;   // float4 index
    int n  = id >> 19;                                // C_*HW_/4 = 2^19
    int p4 = id & 4095;                               // HW_/4
    const float s = 1.0f - *tau_p;
    float4 v = ((const float4*)x)[id];
    uchar4 m = ((const uchar4*)(mask + (size_t)n * HW_))[p4];
    v.x = m.x ? v.x : v.x * s;
    v.y = m.y ? v.y : v.y * s;
    v.z = m.z ? v.z : v.z * s;
    v.w = m.w ? v.w : v.w * s;
    ((float4*)out)[id] = v;
}

extern "C" void kernel_launch(void* const* d_in, const int* in_sizes, int n_in,
                              void* d_out, int out_size, void* d_ws, size_t ws_size,
                              hipStream_t stream) {
    const float* x     = (const float*)d_in[0];
    const float* tau_p = (const float*)d_in[1];
    float* out = (float*)d_out;

    // ws layout: keys (1 MiB) | mask (256 KiB)
    char* ws = (char*)d_ws;
    unsigned*      keys = (unsigned*)ws;
    unsigned char* mask = (unsigned char*)(ws + (size_t)N_ * HW_ * sizeof(unsigned));

    col_mean_kernel<<<(N_ * HW_ / 4) / 256, 256, 0, stream>>>(x, keys);
    select_mask_kernel<<<N_, 256, 0, stream>>>(keys, mask);
    apply_kernel<<<(N_ * C_ * HW_ / 4) / 256, 256, 0, stream>>>(x, mask, tau_p, out);
}

// Round 4
// 255.524 us; speedup vs baseline: 1.1132x; 1.1073x over previous
//
#include <hip/hip_runtime.h>

#define N_ 16
#define C_ 128
#define HW_ 16384
#define K_ 1638   // int(0.1 * 16384)

typedef float nfloat4 __attribute__((ext_vector_type(4)));   // native vec for nontemporal builtin

// order-preserving float -> uint key (larger key <=> larger float)
__device__ __forceinline__ unsigned f2k(float f) {
    unsigned u = __float_as_uint(f);
    return (u & 0x80000000u) ? ~u : (u | 0x80000000u);
}

// Kernel 1: keys[n][p] = f2k(mean over c of x[n][c][p]), fp64 accumulation.
// Channel loop split 4-ways for occupancy: 1024 blocks x 256 thr = 16 waves/CU.
// Block = 64 p4-groups x 4 c-chunks of 32 channels; LDS reduce across chunks.
__global__ __launch_bounds__(256) void col_mean_kernel(const float* __restrict__ x,
                                                       unsigned* __restrict__ keys_g) {
    const int n     = blockIdx.x >> 6;            // 64 blocks per sample
    const int pbase = (blockIdx.x & 63) << 6;     // base p4-group of this block
    const int t     = threadIdx.x;
    const int p4    = pbase + (t & 63);
    const int cch   = t >> 6;                     // 0..3, channel chunk
    const float4* xp = (const float4*)x + (size_t)n * C_ * 4096
                       + (size_t)cch * 32 * 4096 + p4;
    double s0 = 0.0, s1 = 0.0, s2 = 0.0, s3 = 0.0;
    #pragma unroll 16
    for (int cc = 0; cc < 32; ++cc) {
        float4 v = xp[(size_t)cc * 4096];
        s0 += (double)v.x; s1 += (double)v.y; s2 += (double)v.z; s3 += (double)v.w;
    }
    __shared__ double4 part[4][64];
    part[cch][t & 63] = make_double4(s0, s1, s2, s3);
    __syncthreads();
    if (t < 64) {
        double4 a = part[0][t], b = part[1][t], c = part[2][t], d = part[3][t];
        const double inv = 1.0 / (double)C_;
        uint4 r;
        r.x = f2k((float)((a.x + b.x + c.x + d.x) * inv));
        r.y = f2k((float)((a.y + b.y + c.y + d.y) * inv));
        r.z = f2k((float)((a.z + b.z + c.z + d.z) * inv));
        r.w = f2k((float)((a.w + b.w + c.w + d.w) * inv));
        ((uint4*)keys_g)[(size_t)n * 4096 + pbase + t] = r;
    }
}

// Kernel 2: per-sample exact top-k threshold via 4-pass 256-bin radix select
// with keys held in registers (16/thread), then write per-column byte mask.
// Tie-break matches lax.top_k: among keys equal to threshold, lowest index wins.
__global__ __launch_bounds__(1024) void select_mask_kernel(const unsigned* __restrict__ keys_g,
                                                           unsigned char* __restrict__ mask) {
    __shared__ unsigned hist[256];
    __shared__ unsigned Sarr[257];
    __shared__ unsigned selb[2];
    __shared__ unsigned wsum[16];
    const int t    = threadIdx.x;
    const int lane = t & 63;
    const int wid  = t >> 6;
    const int n    = blockIdx.x;

    // thread t owns contiguous keys [t*16, t*16+16)  (index order preserved)
    unsigned kreg[16];
    {
        const uint4* kg = (const uint4*)(keys_g + (size_t)n * HW_);
        #pragma unroll
        for (int j = 0; j < 4; ++j) {
            uint4 v = kg[t * 4 + j];
            kreg[j * 4 + 0] = v.x; kreg[j * 4 + 1] = v.y;
            kreg[j * 4 + 2] = v.z; kreg[j * 4 + 3] = v.w;
        }
    }

    unsigned prefix = 0, need = K_;
    for (int pass = 0; pass < 4; ++pass) {
        const int shift = 24 - 8 * pass;
        const unsigned himask = (pass == 0) ? 0u : (0xFFFFFFFFu << (shift + 8));
        if (t < 256) hist[t] = 0;
        __syncthreads();
        #pragma unroll
        for (int j = 0; j < 16; ++j) {
            unsigned k = kreg[j];
            if (((k ^ prefix) & himask) == 0)
                atomicAdd(&hist[(k >> shift) & 255], 1u);
        }
        __syncthreads();
        if (wid == 0) {
            // wave 0: suffix sums over 256 bins; lane l owns bins [4l, 4l+4)
            unsigned h0 = hist[lane * 4], h1 = hist[lane * 4 + 1];
            unsigned h2 = hist[lane * 4 + 2], h3 = hist[lane * 4 + 3];
            unsigned s3 = h3, s2 = h2 + s3, s1 = h1 + s2, s0 = h0 + s1;
            unsigned run = s0;   // inclusive suffix of lane totals
            #pragma unroll
            for (int off = 1; off < 64; off <<= 1) {
                unsigned v = __shfl_down(run, off, 64);
                if (lane + off < 64) run += v;
            }
            unsigned after = run - s0;   // strictly-after total
            Sarr[lane * 4 + 0] = s0 + after;
            Sarr[lane * 4 + 1] = s1 + after;
            Sarr[lane * 4 + 2] = s2 + after;
            Sarr[lane * 4 + 3] = s3 + after;
            if (lane == 0) Sarr[256] = 0;
        }
        __syncthreads();
        if (t < 256) {
            if (Sarr[t] >= need && Sarr[t + 1] < need) {
                selb[0] = (unsigned)t;
                selb[1] = need - Sarr[t + 1];
            }
        }
        __syncthreads();
        prefix |= selb[0] << shift;
        need = selb[1];
        __syncthreads();
    }
    const unsigned thresh = prefix;   // exact k-th largest key
    const unsigned t_keep = need;     // # of ==thresh elements kept (lowest indices)

    // index-ordered rank among equals: wave shfl scan + cross-wave scan
    unsigned cnt = 0;
    #pragma unroll
    for (int j = 0; j < 16; ++j) cnt += (kreg[j] == thresh) ? 1u : 0u;
    unsigned inc = cnt;
    #pragma unroll
    for (int off = 1; off < 64; off <<= 1) {
        unsigned v = __shfl_up(inc, off, 64);
        if (lane >= off) inc += v;
    }
    if (lane == 63) wsum[wid] = inc;
    __syncthreads();
    if (t == 0) {
        unsigned acc = 0;
        #pragma unroll
        for (int i = 0; i < 16; ++i) { unsigned w = wsum[i]; wsum[i] = acc; acc += w; }
    }
    __syncthreads();
    const unsigned excl = wsum[wid] + inc - cnt;  // equals strictly before my chunk

    unsigned packed[4] = {0, 0, 0, 0};
    unsigned local = 0;
    #pragma unroll
    for (int j = 0; j < 16; ++j) {
        unsigned k = kreg[j];
        unsigned m;
        if (k > thresh) m = 1u;
        else if (k == thresh) { m = ((excl + local) < t_keep) ? 1u : 0u; ++local; }
        else m = 0u;
        packed[j >> 2] |= m << ((j & 3) * 8);
    }
    ((uint4*)(mask + (size_t)n * HW_))[t] = make_uint4(packed[0], packed[1], packed[2], packed[3]);
}

// Kernel 3: out[n][c][p] = mask ? x : x*(1-tau). Nontemporal stores keep x in L3.
__global__ __launch_bounds__(256) void apply_kernel(const float* __restrict__ x,
                                                    const unsigned char* __restrict__ mask,
                                                    const float* __restrict__ tau_p,
                                                    float* __restrict__ out) {
    int id = blockIdx.x * blockDim.x + threadIdx.x;   // float4 index
    int n  = id >> 19;                                // C_*HW_/4 = 2^19
    int p4 = id & 4095;                               // HW_/4
    const float s = 1.0f - *tau_p;
    float4 v = ((const float4*)x)[id];
    uchar4 m = ((const uchar4*)(mask + (size_t)n * HW_))[p4];
    nfloat4 r;
    r.x = m.x ? v.x : v.x * s;
    r.y = m.y ? v.y : v.y * s;
    r.z = m.z ? v.z : v.z * s;
    r.w = m.w ? v.w : v.w * s;
    __builtin_nontemporal_store(r, ((nfloat4*)out) + id);
}

extern "C" void kernel_launch(void* const* d_in, const int* in_sizes, int n_in,
                              void* d_out, int out_size, void* d_ws, size_t ws_size,
                              hipStream_t stream) {
    const float* x     = (const float*)d_in[0];
    const float* tau_p = (const float*)d_in[1];
    float* out = (float*)d_out;

    // ws layout: keys (1 MiB) | mask (256 KiB)
    char* ws = (char*)d_ws;
    unsigned*      keys = (unsigned*)ws;
    unsigned char* mask = (unsigned char*)(ws + (size_t)N_ * HW_ * sizeof(unsigned));

    col_mean_kernel<<<N_ * 64, 256, 0, stream>>>(x, keys);
    select_mask_kernel<<<N_, 1024, 0, stream>>>(keys, mask);
    apply_kernel<<<(N_ * C_ * HW_ / 4) / 256, 256, 0, stream>>>(x, mask, tau_p, out);
}

// Round 5
// 255.163 us; speedup vs baseline: 1.1148x; 1.0014x over previous
//
#include <hip/hip_runtime.h>

#define N_ 16
#define C_ 128
#define HW_ 16384
#define K_ 1638   // int(0.1 * 16384)

typedef float nfloat4 __attribute__((ext_vector_type(4)));   // native vec for nontemporal builtin

// order-preserving float -> uint key (larger key <=> larger float)
__device__ __forceinline__ unsigned f2k(float f) {
    unsigned u = __float_as_uint(f);
    return (u & 0x80000000u) ? ~u : (u | 0x80000000u);
}

// Kernel 1: keys[n][p] = f2k(mean over c of x[n][c][p]), fp64 accumulation.
// 1024 blocks x 256 thr; __launch_bounds__(256,4) pins 4 waves/EU = 4 blocks/CU
// so the register allocator cannot drop occupancy below 16 waves/CU.
__global__ __launch_bounds__(256, 4) void col_mean_kernel(const float* __restrict__ x,
                                                          unsigned* __restrict__ keys_g) {
    const int n     = blockIdx.x >> 6;            // 64 blocks per sample
    const int pbase = (blockIdx.x & 63) << 6;     // base p4-group of this block
    const int t     = threadIdx.x;
    const int p4    = pbase + (t & 63);
    const int cch   = t >> 6;                     // 0..3, channel chunk
    const float4* xp = (const float4*)x + (size_t)n * C_ * 4096
                       + (size_t)cch * 32 * 4096 + p4;
    double s0 = 0.0, s1 = 0.0, s2 = 0.0, s3 = 0.0;
    #pragma unroll 8
    for (int cc = 0; cc < 32; ++cc) {
        float4 v = xp[(size_t)cc * 4096];
        s0 += (double)v.x; s1 += (double)v.y; s2 += (double)v.z; s3 += (double)v.w;
    }
    __shared__ double4 part[4][64];
    part[cch][t & 63] = make_double4(s0, s1, s2, s3);
    __syncthreads();
    if (t < 64) {
        double4 a = part[0][t], b = part[1][t], c = part[2][t], d = part[3][t];
        const double inv = 1.0 / (double)C_;
        uint4 r;
        r.x = f2k((float)((a.x + b.x + c.x + d.x) * inv));
        r.y = f2k((float)((a.y + b.y + c.y + d.y) * inv));
        r.z = f2k((float)((a.z + b.z + c.z + d.z) * inv));
        r.w = f2k((float)((a.w + b.w + c.w + d.w) * inv));
        ((uint4*)keys_g)[(size_t)n * 4096 + pbase + t] = r;
    }
}

// Kernel 2: per-sample exact top-k threshold via 4-pass 256-bin radix select
// with keys held in registers (16/thread), then write per-column byte mask.
// Tie-break matches lax.top_k: among keys equal to threshold, lowest index wins.
__global__ __launch_bounds__(1024) void select_mask_kernel(const unsigned* __restrict__ keys_g,
                                                           unsigned char* __restrict__ mask) {
    __shared__ unsigned hist[256];
    __shared__ unsigned Sarr[257];
    __shared__ unsigned selb[2];
    __shared__ unsigned wsum[16];
    const int t    = threadIdx.x;
    const int lane = t & 63;
    const int wid  = t >> 6;
    const int n    = blockIdx.x;

    // thread t owns contiguous keys [t*16, t*16+16)  (index order preserved)
    unsigned kreg[16];
    {
        const uint4* kg = (const uint4*)(keys_g + (size_t)n * HW_);
        #pragma unroll
        for (int j = 0; j < 4; ++j) {
            uint4 v = kg[t * 4 + j];
            kreg[j * 4 + 0] = v.x; kreg[j * 4 + 1] = v.y;
            kreg[j * 4 + 2] = v.z; kreg[j * 4 + 3] = v.w;
        }
    }

    unsigned prefix = 0, need = K_;
    for (int pass = 0; pass < 4; ++pass) {
        const int shift = 24 - 8 * pass;
        const unsigned himask = (pass == 0) ? 0u : (0xFFFFFFFFu << (shift + 8));
        if (t < 256) hist[t] = 0;
        __syncthreads();
        #pragma unroll
        for (int j = 0; j < 16; ++j) {
            unsigned k = kreg[j];
            if (((k ^ prefix) & himask) == 0)
                atomicAdd(&hist[(k >> shift) & 255], 1u);
        }
        __syncthreads();
        if (wid == 0) {
            // wave 0: suffix sums over 256 bins; lane l owns bins [4l, 4l+4)
            unsigned h0 = hist[lane * 4], h1 = hist[lane * 4 + 1];
            unsigned h2 = hist[lane * 4 + 2], h3 = hist[lane * 4 + 3];
            unsigned s3 = h3, s2 = h2 + s3, s1 = h1 + s2, s0 = h0 + s1;
            unsigned run = s0;   // inclusive suffix of lane totals
            #pragma unroll
            for (int off = 1; off < 64; off <<= 1) {
                unsigned v = __shfl_down(run, off, 64);
                if (lane + off < 64) run += v;
            }
            unsigned after = run - s0;   // strictly-after total
            Sarr[lane * 4 + 0] = s0 + after;
            Sarr[lane * 4 + 1] = s1 + after;
            Sarr[lane * 4 + 2] = s2 + after;
            Sarr[lane * 4 + 3] = s3 + after;
            if (lane == 0) Sarr[256] = 0;
        }
        __syncthreads();
        if (t < 256) {
            if (Sarr[t] >= need && Sarr[t + 1] < need) {
                selb[0] = (unsigned)t;
                selb[1] = need - Sarr[t + 1];
            }
        }
        __syncthreads();
        prefix |= selb[0] << shift;
        need = selb[1];
        __syncthreads();
    }
    const unsigned thresh = prefix;   // exact k-th largest key
    const unsigned t_keep = need;     // # of ==thresh elements kept (lowest indices)

    // index-ordered rank among equals: wave shfl scan + cross-wave scan
    unsigned cnt = 0;
    #pragma unroll
    for (int j = 0; j < 16; ++j) cnt += (kreg[j] == thresh) ? 1u : 0u;
    unsigned inc = cnt;
    #pragma unroll
    for (int off = 1; off < 64; off <<= 1) {
        unsigned v = __shfl_up(inc, off, 64);
        if (lane >= off) inc += v;
    }
    if (lane == 63) wsum[wid] = inc;
    __syncthreads();
    if (t == 0) {
        unsigned acc = 0;
        #pragma unroll
        for (int i = 0; i < 16; ++i) { unsigned w = wsum[i]; wsum[i] = acc; acc += w; }
    }
    __syncthreads();
    const unsigned excl = wsum[wid] + inc - cnt;  // equals strictly before my chunk

    unsigned packed[4] = {0, 0, 0, 0};
    unsigned local = 0;
    #pragma unroll
    for (int j = 0; j < 16; ++j) {
        unsigned k = kreg[j];
        unsigned m;
        if (k > thresh) m = 1u;
        else if (k == thresh) { m = ((excl + local) < t_keep) ? 1u : 0u; ++local; }
        else m = 0u;
        packed[j >> 2] |= m << ((j & 3) * 8);
    }
    ((uint4*)(mask + (size_t)n * HW_))[t] = make_uint4(packed[0], packed[1], packed[2], packed[3]);
}

// Kernel 3: out[n][c][p] = mask ? x : x*(1-tau). Nontemporal stores keep x in L3
// (x is L3-resident from col_mean's read; out bypasses so it doesn't evict x).
__global__ __launch_bounds__(256) void apply_kernel(const float* __restrict__ x,
                                                    const unsigned char* __restrict__ mask,
                                                    const float* __restrict__ tau_p,
                                                    float* __restrict__ out) {
    int id = blockIdx.x * blockDim.x + threadIdx.x;   // float4 index
    int n  = id >> 19;                                // C_*HW_/4 = 2^19
    int p4 = id & 4095;                               // HW_/4
    const float s = 1.0f - *tau_p;
    float4 v = ((const float4*)x)[id];
    uchar4 m = ((const uchar4*)(mask + (size_t)n * HW_))[p4];
    nfloat4 r;
    r.x = m.x ? v.x : v.x * s;
    r.y = m.y ? v.y : v.y * s;
    r.z = m.z ? v.z : v.z * s;
    r.w = m.w ? v.w : v.w * s;
    __builtin_nontemporal_store(r, ((nfloat4*)out) + id);
}

extern "C" void kernel_launch(void* const* d_in, const int* in_sizes, int n_in,
                              void* d_out, int out_size, void* d_ws, size_t ws_size,
                              hipStream_t stream) {
    const float* x     = (const float*)d_in[0];
    const float* tau_p = (const float*)d_in[1];
    float* out = (float*)d_out;

    // ws layout: keys (1 MiB) | mask (256 KiB)
    char* ws = (char*)d_ws;
    unsigned*      keys = (unsigned*)ws;
    unsigned char* mask = (unsigned char*)(ws + (size_t)N_ * HW_ * sizeof(unsigned));

    col_mean_kernel<<<N_ * 64, 256, 0, stream>>>(x, keys);
    select_mask_kernel<<<N_, 1024, 0, stream>>>(keys, mask);
    apply_kernel<<<(N_ * C_ * HW_ / 4) / 256, 256, 0, stream>>>(x, mask, tau_p, out);
}